// Round 1
// 656.502 us; speedup vs baseline: 1.0421x; 1.0421x over previous
//
#include <hip/hip_runtime.h>
#include <stdint.h>

// Problem constants (from reference setup_inputs)
#define NQ      256        // D: number of query descriptors
#define NC      256        // C: descriptor dim
#define NDB     500000     // N: db rows
#define ROWLEN  257        // places_db row stride (256 dims + id)
#define MIN_SIM_F 0.8f
#define NMS_THR   0.8f
#define CAP     64         // candidate capacity per query
#define TILE    32         // db rows per GEMM tile (500000/32 = 15625 exact)
#define NTILES  (NDB / TILE)
#define BLK     512
#define GEMM_GRID 512      // 2 blocks/CU

typedef __bf16 bf16x8 __attribute__((ext_vector_type(8)));
typedef float  f32x4  __attribute__((ext_vector_type(4)));

union BU { unsigned short u[8]; bf16x8 v; };

__device__ __forceinline__ unsigned short f2bf(float f) {
    uint32_t u = __float_as_uint(f);
    u += 0x7FFFu + ((u >> 16) & 1u);   // round-to-nearest-even
    return (unsigned short)(u >> 16);
}

// ---------------------------------------------------------------------------
// Kernel 0: zero the per-query candidate counters (ws is poisoned 0xAA)
// ---------------------------------------------------------------------------
__global__ void init_counts(int* cnt) { cnt[threadIdx.x] = 0; }

// ---------------------------------------------------------------------------
// Kernel 1: bf16-MFMA GEMM (q @ X^T) with >=MIN_SIM filter.
// 512 threads = 8 waves; wave w owns queries [w*32, w*32+32) as persistent
// register A-fragments (a[2][8] = 64 VGPR).
//
// R3 restructure (this round): row-aligned staging, TILE 16->32.
//   - thread (r=tid>>4, j=tid&15) owns db row r of the tile, cols j*16..+15:
//     4 contiguous dwordx4 global loads, id column (col 256) never staged.
//     -> no div-by-257, no wrap check, LDS write = 2x ds_write_b128.
//   - TILE=32 halves barrier count vs TILE=16 and doubles the MFMA phase
//     that hides HBM latency of the next tile's in-flight loads.
// Double-buffered LDS, register prefetch: issue loads for tile t+1 ->
// MFMA tile t -> cvt+ds_write -> one barrier per tile.
// Register budget: A 64 + acc 16 + prefetch 16 + misc ~25 = ~120 < 128 cap.
// mfma_f32_16x16x32_bf16 layouts (verified in prior rounds, absmax 0):
//   A: lane holds A[m=lane&15][k=(lane>>4)*8+j]
//   B: lane holds B[k=(lane>>4)*8+j][n=lane&15]
//   D: D[row=(lane>>4)*4+r][col=lane&15]
// ---------------------------------------------------------------------------
__global__ __launch_bounds__(BLK, 4) void gemm_filter(
    const float* __restrict__ q, const float* __restrict__ db,
    int* __restrict__ cnt, float* __restrict__ csim, int* __restrict__ cidx)
{
    // Row stride 264 bf16 = 528 B: every row 16B-aligned (528 % 16 == 0);
    // ds_read_b128 start banks spread, worst 2-way (free per m136).
    __shared__ __align__(16) unsigned short Bs[2][TILE][264];

    const int tid  = threadIdx.x;
    const int wave = tid >> 6;      // 0..7
    const int lane = tid & 63;
    const int quad = lane >> 4;
    const int l16  = lane & 15;
    const int rrow = tid >> 4;      // 0..31  staging row within tile
    const int jcol = tid & 15;      // 0..15  staging col group (16 floats)

    // Persistent A fragments: wave w covers queries [w*32, w*32+32)
    bf16x8 a[2][8];
    #pragma unroll
    for (int f = 0; f < 2; ++f) {
        const int m = wave * 32 + f * 16 + l16;
        const float* qrow = q + m * NC;
        #pragma unroll
        for (int s = 0; s < 8; ++s) {
            const int k0 = s * 32 + quad * 8;
            BU u;
            #pragma unroll
            for (int j = 0; j < 8; ++j) u.u[j] = f2bf(qrow[k0 + j]);
            a[f][s] = u.v;
        }
    }

    // Prefetch registers: 16 floats/thread (row rrow, cols jcol*16..+15)
    f32x4 p0, p1, p2, p3;

    auto LOAD = [&](int tile) {
        const float* s = db + ((size_t)tile * TILE + rrow) * ROWLEN + jcol * 16;
        p0 = *(const f32x4*)(s + 0);
        p1 = *(const f32x4*)(s + 4);
        p2 = *(const f32x4*)(s + 8);
        p3 = *(const f32x4*)(s + 12);
    };

    auto WRITE = [&](int nb) {
        union { unsigned short u[8]; uint4 v; } w0, w1;
        #pragma unroll
        for (int e = 0; e < 4; ++e) {
            w0.u[e]     = f2bf(p0[e]);
            w0.u[4 + e] = f2bf(p1[e]);
            w1.u[e]     = f2bf(p2[e]);
            w1.u[4 + e] = f2bf(p3[e]);
        }
        uint4* dst = (uint4*)&Bs[nb][rrow][jcol * 16];
        dst[0] = w0.v;      // ds_write_b128, 16B-aligned
        dst[1] = w1.v;
    };

    auto COMPUTE = [&](int cb, int tile) {
        const f32x4 zero = {0.f, 0.f, 0.f, 0.f};
        f32x4 acc[2][2] = {{zero, zero}, {zero, zero}};
        #pragma unroll
        for (int s = 0; s < 8; ++s) {
            const bf16x8 b0 = *(const bf16x8*)&Bs[cb][l16][s * 32 + quad * 8];
            const bf16x8 b1 = *(const bf16x8*)&Bs[cb][16 + l16][s * 32 + quad * 8];
            acc[0][0] = __builtin_amdgcn_mfma_f32_16x16x32_bf16(a[0][s], b0, acc[0][0], 0, 0, 0);
            acc[1][0] = __builtin_amdgcn_mfma_f32_16x16x32_bf16(a[1][s], b0, acc[1][0], 0, 0, 0);
            acc[0][1] = __builtin_amdgcn_mfma_f32_16x16x32_bf16(a[0][s], b1, acc[0][1], 0, 0, 0);
            acc[1][1] = __builtin_amdgcn_mfma_f32_16x16x32_bf16(a[1][s], b1, acc[1][1], 0, 0, 0);
        }
        // Filter epilogue: wave-rare fast path (max sim in data ~0.38 << 0.8)
        float mx = acc[0][0][0];
        #pragma unroll
        for (int fm = 0; fm < 2; ++fm)
            #pragma unroll
            for (int h = 0; h < 2; ++h)
                #pragma unroll
                for (int rr = 0; rr < 4; ++rr) mx = fmaxf(mx, acc[fm][h][rr]);
        if (mx >= MIN_SIM_F) {
            #pragma unroll
            for (int fm = 0; fm < 2; ++fm) {
                #pragma unroll
                for (int h = 0; h < 2; ++h) {
                    #pragma unroll
                    for (int rr = 0; rr < 4; ++rr) {
                        const float sv = acc[fm][h][rr];
                        if (sv >= MIN_SIM_F) {
                            const int qi   = wave * 32 + fm * 16 + quad * 4 + rr;
                            const int rowg = tile * TILE + h * 16 + l16;
                            const int pos = atomicAdd(&cnt[qi], 1);
                            if (pos < CAP) {
                                csim[qi * CAP + pos] = sv;
                                cidx[qi * CAP + pos] = rowg;
                            }
                        }
                    }
                }
            }
        }
    };

    int tile = blockIdx.x;
    LOAD(tile);
    WRITE(0);
    __syncthreads();
    int buf = 0;
    for (;;) {
        const int next = tile + GEMM_GRID;
        const bool more = (next < NTILES);
        if (more) LOAD(next);        // loads in flight across the MFMA phase
        COMPUTE(buf, tile);
        if (!more) break;
        WRITE(buf ^ 1);              // s_waitcnt vmcnt here, not at barrier
        __syncthreads();
        buf ^= 1;
        tile = next;
    }
}

// ---------------------------------------------------------------------------
// Kernel 2: per-query top-10 + voting + NMS + outputs. One block, 256 threads.
// ---------------------------------------------------------------------------
__device__ __forceinline__ bool better(float s1, int i1, float s2, int i2) {
    return (s1 > s2) || (s1 == s2 && i1 < i2);   // lax.top_k tie-break
}

__global__ __launch_bounds__(256) void postprocess(
    const float* __restrict__ boxes, const float* __restrict__ db,
    const int* __restrict__ cnt, const float* __restrict__ csim,
    const int* __restrict__ cidx, float* __restrict__ out)
{
    __shared__ int   lab[NQ];
    __shared__ float area_s[NQ];
    __shared__ float bx[NQ][4];

    const int q = threadIdx.x;

    // ---- exact top-10 by (sim desc, idx asc) via insertion ----
    float s10[10]; int i10[10];
    int k = 0;
    int c = cnt[q]; if (c > CAP) c = CAP;
    for (int j = 0; j < c; ++j) {
        const float s = csim[q * CAP + j];
        const int   ix = cidx[q * CAP + j];
        int p;
        if (k < 10) { p = k; ++k; }
        else { if (!better(s, ix, s10[9], i10[9])) continue; p = 9; }
        while (p > 0 && better(s, ix, s10[p - 1], i10[p - 1])) {
            s10[p] = s10[p - 1]; i10[p] = i10[p - 1]; --p;
        }
        s10[p] = s; i10[p] = ix;
    }

    // ---- voting (all candidates already >= MIN_SIM) ----
    int vid[10];
    for (int j = 0; j < k; ++j) vid[j] = (int)db[(size_t)i10[j] * ROWLEN + (ROWLEN - 1)];
    int best_cnt = 0, best_id = 0x7fffffff;
    for (int j = 0; j < k; ++j) {
        int cj = 0;
        for (int l = 0; l < k; ++l) cj += (vid[l] == vid[j]) ? 1 : 0;
        if (cj > best_cnt || (cj == best_cnt && vid[j] < best_id)) { best_cnt = cj; best_id = vid[j]; }
    }
    const int lq = (best_cnt > 0) ? best_id : -1;   // MIN_VOTES=0
    lab[q] = lq;

    const float x1 = boxes[q * 4 + 0], y1 = boxes[q * 4 + 1];
    const float x2 = boxes[q * 4 + 2], y2 = boxes[q * 4 + 3];
    bx[q][0] = x1; bx[q][1] = y1; bx[q][2] = x2; bx[q][3] = y2;
    const float aq = (x2 - x1) * (y2 - y1);
    area_s[q] = aq;
    __syncthreads();

    // ---- NMS: remove q if exists p!=q, same label>=0, overlap>=thr, area_p <= area_q
    bool rem = false;
    if (lq >= 0) {
        for (int p = 0; p < NQ; ++p) {
            if (p == q || lab[p] != lq) continue;
            const float ap = area_s[p];
            if (ap > aq) continue;
            const float xi1 = fmaxf(x1, bx[p][0]);
            const float yi1 = fmaxf(y1, bx[p][1]);
            const float xi2 = fminf(x2, bx[p][2]);
            const float yi2 = fminf(y2, bx[p][3]);
            const float inter = fmaxf(xi2 - xi1, 0.f) * fmaxf(yi2 - yi1, 0.f);
            const float small = fminf(aq, ap);
            const float ov = (small > 0.f) ? inter / small : 0.f;
            if (ov >= NMS_THR) { rem = true; break; }
        }
    }
    const int lq2 = rem ? -1 : lq;

    // ---- sim_scores with final labels ----
    float score = 0.f;
    if (lq2 >= 0)
        for (int j = 0; j < k; ++j)
            if (vid[j] == lq2) score = fmaxf(score, s10[j]);

    // ---- outputs: [boxes 1024][sim_scores 256][results 256] as float32 ----
    for (int t = q; t < NQ * 4; t += NQ) out[t] = boxes[t];
    out[NQ * 4 + q] = score;
    out[NQ * 5 + q] = (float)lq2;
}

// ---------------------------------------------------------------------------
extern "C" void kernel_launch(void* const* d_in, const int* in_sizes, int n_in,
                              void* d_out, int out_size, void* d_ws, size_t ws_size,
                              hipStream_t stream) {
    const float* boxes = (const float*)d_in[0];   // final_boxes (256,4)
    const float* desc  = (const float*)d_in[1];   // descriptors (256,256)
    const float* db    = (const float*)d_in[2];   // places_db  (500000,257)
    float* out = (float*)d_out;

    int*   cnt  = (int*)d_ws;                                   // 256 ints
    float* csim = (float*)((char*)d_ws + 1024);                 // 256*CAP floats
    int*   cidx = (int*)((char*)d_ws + 1024 + NQ * CAP * 4);    // 256*CAP ints

    init_counts<<<1, 256, 0, stream>>>(cnt);
    gemm_filter<<<GEMM_GRID, BLK, 0, stream>>>(desc, db, cnt, csim, cidx);
    postprocess<<<1, 256, 0, stream>>>(boxes, db, cnt, csim, cidx, out);
}